// Round 3
// baseline (117.238 us; speedup 1.0000x reference)
//
#include <hip/hip_runtime.h>
#include <math.h>

// Round 3: same algebraic collapse (sum(G) = ||sum_n Hn||^2, trace(G)=N), but
// dispatch-count 6 -> 3 and fast-math transcendentals:
//   D1: hipMemsetAsync of 32 KB accumulator region
//   D2: fused kernel: column sums-of-squares of H (256 blocks) + CE (32 blocks)
//   D3: GEMV s[d] = sum_n H[d][n]*rsqrt(norms2[n]); last-block-done finalize
// Rationale: round-2 profile showed the timed window dominated by harness
// fills (43 us, 256 MiB poison) + a 6-deep serial dispatch chain. Fewer nodes
// + rsqrtf (1 instr vs ~20 for precise 1/sqrt) trims everything that is ours.

#define N_COLS  8192
#define D_ROWS  1024
#define B_ROWS  8192
#define CSS_BLOCKS   256   // colsumsq blocks: 8 col-groups x 32 row-groups
#define CSS_ROWS_PER  32
#define CE_BLOCKS    32    // 32 x 256 threads = 8192 = B_ROWS
#define GEMV_BLOCKS  1024  // one per row d

// ---------------------------------------------------------------------------
__device__ inline float block_reduce_sum_256(float v) {
    #pragma unroll
    for (int off = 32; off > 0; off >>= 1) v += __shfl_down(v, off, 64);
    __shared__ float sm[4];
    int lane = threadIdx.x & 63;
    int wid  = threadIdx.x >> 6;
    if (lane == 0) sm[wid] = v;
    __syncthreads();
    if (threadIdx.x < 4) {
        v = sm[threadIdx.x];
        v += __shfl_down(v, 2, 64);
        v += __shfl_down(v, 1, 64);
    }
    return v;
}

// ---------------------------------------------------------------------------
// Fused: blocks [0,256) do column sums of squares; blocks [256,288) do CE.
__global__ __launch_bounds__(256)
void colsumsq_ce_kernel(const float* __restrict__ H,
                        const float* __restrict__ logits,
                        const int* __restrict__ labels,
                        float* __restrict__ norms2,
                        float* __restrict__ ce_acc) {
    if (blockIdx.x < CSS_BLOCKS) {
        // ---- column sums of squares ----
        const int cg = blockIdx.x & 7;          // col-group: 1024 cols
        const int rg = blockIdx.x >> 3;         // row-group: 32 rows
        const int col4 = cg * 256 + threadIdx.x;
        const int row0 = rg * CSS_ROWS_PER;
        const float4* __restrict__ H4 = (const float4*)H;
        float ax = 0.f, ay = 0.f, az = 0.f, aw = 0.f;
        #pragma unroll
        for (int r = 0; r < CSS_ROWS_PER; ++r) {
            float4 v = H4[(size_t)(row0 + r) * (N_COLS / 4) + col4];
            ax = fmaf(v.x, v.x, ax);
            ay = fmaf(v.y, v.y, ay);
            az = fmaf(v.z, v.z, az);
            aw = fmaf(v.w, v.w, aw);
        }
        const int col = col4 * 4;
        atomicAdd(&norms2[col + 0], ax);
        atomicAdd(&norms2[col + 1], ay);
        atomicAdd(&norms2[col + 2], az);
        atomicAdd(&norms2[col + 3], aw);
    } else {
        // ---- cross-entropy over [B, 2] ----
        const int b = (blockIdx.x - CSS_BLOCKS) * 256 + threadIdx.x;  // covers B
        float2 x = ((const float2*)logits)[b];
        float m = fmaxf(x.x, x.y);
        float lse = m + __logf(__expf(x.x - m) + __expf(x.y - m));
        float xl = (labels[b] == 0) ? x.x : x.y;
        float s = block_reduce_sum_256(lse - xl);
        if (threadIdx.x == 0) atomicAdd(ce_acc, s);
    }
}

// ---------------------------------------------------------------------------
// GEMV + finalize-on-last-block.
// s[d] = sum_n H[d][n] * rsqrt(norms2[n]);  s2 += s[d]^2.
// The block that sees done_cnt == GEMV_BLOCKS-1 computes the final scalar.
__global__ __launch_bounds__(256)
void gemv_s2_finalize_kernel(const float* __restrict__ H,
                             const float* __restrict__ norms2,
                             float* __restrict__ s2_acc,
                             const float* __restrict__ ce_acc,
                             unsigned int* __restrict__ done_cnt,
                             float* __restrict__ out) {
    const int d = blockIdx.x;
    const float4* __restrict__ Hrow = (const float4*)(H + (size_t)d * N_COLS);
    const float4* __restrict__ n24  = (const float4*)norms2;
    float acc = 0.f;
    #pragma unroll
    for (int i = threadIdx.x; i < N_COLS / 4; i += 256) {
        float4 v  = Hrow[i];
        float4 n2 = n24[i];
        // norms ~ sqrt(D) >> eps, so rsqrtf == 1/max(sqrt(n2), 1e-12) here;
        // clamp only to dodge div-by-zero pathology.
        acc = fmaf(v.x, rsqrtf(fmaxf(n2.x, 1e-24f)), acc);
        acc = fmaf(v.y, rsqrtf(fmaxf(n2.y, 1e-24f)), acc);
        acc = fmaf(v.z, rsqrtf(fmaxf(n2.z, 1e-24f)), acc);
        acc = fmaf(v.w, rsqrtf(fmaxf(n2.w, 1e-24f)), acc);
    }
    float s = block_reduce_sum_256(acc);
    __shared__ bool last;
    if (threadIdx.x == 0) {
        atomicAdd(s2_acc, s * s);
        __threadfence();
        unsigned int old = atomicAdd(done_cnt, 1u);
        last = (old == GEMV_BLOCKS - 1);
    }
    __syncthreads();
    if (last && threadIdx.x == 0) {
        float s2 = atomicAdd(s2_acc, 0.f);   // coherent read of final sum
        float ce = atomicAdd((float*)ce_acc, 0.f);
        double reg = ((double)s2 - (double)N_COLS) * 0.5
                     / ((double)N_COLS * (double)(N_COLS - 1));
        out[0] = (float)((double)ce / (double)B_ROWS + reg);
    }
}

// ---------------------------------------------------------------------------
extern "C" void kernel_launch(void* const* d_in, const int* in_sizes, int n_in,
                              void* d_out, int out_size, void* d_ws, size_t ws_size,
                              hipStream_t stream) {
    const float* outputs = (const float*)d_in[0];   // [B, 2] f32
    const int*   labels  = (const int*)d_in[1];     // [B]
    const float* H       = (const float*)d_in[2];   // [D, N] f32
    float* out = (float*)d_out;

    // ws layout: norms2[N] | s2_acc | ce_acc | done_cnt
    float* norms2 = (float*)d_ws;
    float* s2_acc = norms2 + N_COLS;
    float* ce_acc = s2_acc + 1;
    unsigned int* done_cnt = (unsigned int*)(ce_acc + 1);

    hipMemsetAsync(d_ws, 0, (N_COLS + 3) * sizeof(float), stream);

    colsumsq_ce_kernel<<<CSS_BLOCKS + CE_BLOCKS, 256, 0, stream>>>(
        H, outputs, labels, norms2, ce_acc);
    gemv_s2_finalize_kernel<<<GEMV_BLOCKS, 256, 0, stream>>>(
        H, norms2, s2_acc, ce_acc, done_cnt, out);
}